// Round 4
// baseline (537.131 us; speedup 1.0000x reference)
//
#include <hip/hip_runtime.h>
#include <hip/hip_bf16.h>
#include <math.h>

// Problem constants (from reference)
#define D 64
#define K 512
#define NROWS 65536
#define DECAY 0.99f
#define ONE_MINUS_DECAY (1.0f - 0.99f)
#define COMMIT 0.25f

// ws layout (float offsets)
#define WS_DWT    0              // [K][D] = 32768  dw accumulator (transposed)
#define WS_COUNTS 32768          // [K]   = 512     cluster counts
#define WS_LOSS   33280          // [1]             loss sum (pad to 33344)
#define WS_ESQ    33344          // [K]   = 512     ||e_k||^2
#define WS_ET     33856          // [K][D]= 32768   embeddings transposed
#define WS_STABLE 66624          // [K]   = 512     stable_cs
#define WS_DEBIAS 67136          // [1]             debias factor
#define WS_ZERO_FLOATS 33344     // zero region: dw_t + counts + loss (+pad)

// out layout (float offsets)
#define OUT_Q     0              // quantized_st [N][D]
#define OUT_LOSS  4194304
#define OUT_PERP  4194305
#define OUT_IDX   4194306        // [N] indices as float
#define OUT_NEMB  4259842        // new_embeddings [D][K]
#define OUT_HCS   4292610        // hid_cs [K]
#define OUT_HDW   4293122       // hid_dw [D][K]

#define RPB 128                  // rows per block (waves 0,1 = cols 0:256; 2,3 = 256:512)

// ---------------- prep: zero accumulators + transpose emb + col norms -------
__global__ void vq_prep(const float* __restrict__ emb,  // [D][K]
                        float* __restrict__ ws)
{
    int i = blockIdx.x * 256 + threadIdx.x;   // 0..32767 (128 blocks)
    if (i < WS_ZERO_FLOATS / 4) {             // zero dw_t + counts + loss
        ((float4*)ws)[i] = make_float4(0.f, 0.f, 0.f, 0.f);
    }
    // coalesced transpose: read emb[i] contiguously, scatter to e_t
    {
        int d = i >> 9, k = i & (K - 1);
        ws[WS_ET + k * D + d] = emb[i];
    }
    if (i < K) {                              // ||e_k||^2 (coalesced over k)
        float s = 0.f;
        for (int d = 0; d < D; ++d) { float v = emb[d * K + i]; s += v * v; }
        ws[WS_ESQ + i] = s;
    }
}

// ---------------- main: scalar-e / register-x distances + argmin + tail ------
__global__ __launch_bounds__(256, 2)
void vq_main(const float* __restrict__ x,     // [N][D]
             const float* __restrict__ e_t,   // [K][D]
             const float* __restrict__ e_sq,  // [K]
             float* __restrict__ out_q,       // [N][D]
             float* __restrict__ out_idx,     // [N] (float)
             float* __restrict__ dw_t,        // [K][D] atomic accum
             float* __restrict__ counts,      // [K]  atomic accum
             float* __restrict__ loss_sum)    // [1]  atomic accum
{
    __shared__ float s_best[RPB];
    __shared__ int   s_bestk[RPB];

    const int tid  = threadIdx.x;
    const int lane = tid & 63;
    const int wv   = tid >> 6;                 // 0..3
    const int half = wv >> 1;                  // 0 or 1 (codebook half)
    const int rloc = ((wv & 1) << 6) + lane;   // 0..127
    const int row  = blockIdx.x * RPB + rloc;
    // per-wave-uniform codebook base; force scalarization
    const int jbase = __builtin_amdgcn_readfirstlane(half << 8);

    // x row -> registers (fully unrolled so xr stays in VGPRs)
    float xr[D];
    {
        const float4* xp = (const float4*)(x + (size_t)row * D);
#pragma unroll
        for (int i = 0; i < 16; ++i) {
            float4 v = xp[i];
            xr[4 * i + 0] = v.x; xr[4 * i + 1] = v.y;
            xr[4 * i + 2] = v.z; xr[4 * i + 3] = v.w;
        }
    }

    float best = 3.0e38f;
    int   bestk = 0;

#pragma unroll 2
    for (int j4 = 0; j4 < K / 2; j4 += 4) {
        const float* ec = e_t + (size_t)(jbase + j4) * D;  // wave-uniform -> s_load
        float a0 = 0.f, a1 = 0.f, a2 = 0.f, a3 = 0.f;
#pragma unroll
        for (int d = 0; d < D; ++d) {
            float xv = xr[d];
            a0 = fmaf(xv, ec[d], a0);
            a1 = fmaf(xv, ec[D + d], a1);
            a2 = fmaf(xv, ec[2 * D + d], a2);
            a3 = fmaf(xv, ec[3 * D + d], a3);
        }
        float acc[4] = {a0, a1, a2, a3};
#pragma unroll
        for (int c = 0; c < 4; ++c) {
            float s = e_sq[jbase + j4 + c] - 2.0f * acc[c];
            if (s < best) { best = s; bestk = jbase + j4 + c; }  // ascending k
        }
    }

    // combine halves: upper half publishes, lower half wins ties (lower k)
    if (half == 1) { s_best[rloc] = best; s_bestk[rloc] = bestk; }
    __syncthreads();

    float lsum = 0.f;
    if (half == 0) {
        float ob = s_best[rloc];
        if (ob < best) { best = ob; bestk = s_bestk[rloc]; }

        out_idx[row] = (float)bestk;
        atomicAdd(&counts[bestk], 1.0f);

        const float4* ep = (const float4*)(e_t + (size_t)bestk * D);
        float4* qp = (float4*)(out_q + (size_t)row * D);
#pragma unroll
        for (int i = 0; i < 16; ++i) {
            float4 q = ep[i];
            float d0 = q.x - xr[4 * i + 0], d1 = q.y - xr[4 * i + 1];
            float d2 = q.z - xr[4 * i + 2], d3 = q.w - xr[4 * i + 3];
            lsum += d0 * d0 + d1 * d1 + d2 * d2 + d3 * d3;
            qp[i] = q;
        }
        // dw scatter from registers
#pragma unroll
        for (int d = 0; d < D; ++d)
            atomicAdd(&dw_t[bestk * D + d], xr[d]);
    }

    // loss: waves 0,1 hold nonzero partials; reduce per wave, one atomic each
    if (wv < 2) {
        for (int m = 32; m >= 1; m >>= 1) lsum += __shfl_xor(lsum, m, 64);
        if (lane == 0) atomicAdd(loss_sum, lsum);
    }
}

// ---------------- finalize A: scalars (1 block) ------------------------------
__global__ void vq_final_a(const float* __restrict__ counts,
                           const float* __restrict__ loss_sum,
                           const float* __restrict__ ema_csh,  // [K]
                           const int*   __restrict__ counter,
                           float* __restrict__ out_loss,
                           float* __restrict__ out_perp,
                           float* __restrict__ out_hcs,        // [K]
                           float* __restrict__ ws_stable,      // [K]
                           float* __restrict__ ws_debias)      // [1]
{
    __shared__ float s_red[K];

    const int k = threadIdx.x;  // 512 threads
    const float c = counts[k];
    const float hid = ema_csh[k] * DECAY + c * ONE_MINUS_DECAY;
    out_hcs[k] = hid;

    const int   cnt    = counter[0] + 1;
    const float debias = 1.0f - powf(DECAY, (float)cnt);
    const float upd    = hid / debias;

    s_red[k] = upd;
    __syncthreads();
    for (int off = 256; off >= 1; off >>= 1) {
        if (k < off) s_red[k] += s_red[k + off];
        __syncthreads();
    }
    const float n = s_red[0];
    __syncthreads();

    const float p = c * (1.0f / (float)NROWS);
    s_red[k] = p * logf(p + 1e-10f);
    __syncthreads();
    for (int off = 256; off >= 1; off >>= 1) {
        if (k < off) s_red[k] += s_red[k + off];
        __syncthreads();
    }
    const float ent = s_red[0];

    ws_stable[k] = (upd + 1e-5f) / (n + (float)K * 1e-5f) * n;
    if (k == 0) {
        ws_debias[0] = debias;
        out_loss[0]  = COMMIT * loss_sum[0] / (float)((size_t)NROWS * D);
        out_perp[0]  = expf(-ent);
    }
}

// ---------------- finalize B: hdw + new embeddings (parallel) ----------------
__global__ void vq_final_b(const float* __restrict__ dw_t,      // [K][D]
                           const float* __restrict__ ema_dwh,   // [D][K]
                           const float* __restrict__ ws_stable, // [K]
                           const float* __restrict__ ws_debias,
                           float* __restrict__ out_nemb,        // [D][K]
                           float* __restrict__ out_hdw)         // [D][K]
{
    int i = blockIdx.x * 256 + threadIdx.x;  // 0..32767 (128 blocks)
    int d = i >> 9, kk = i & (K - 1);
    float hdw = ema_dwh[i] * DECAY + dw_t[kk * D + d] * ONE_MINUS_DECAY;
    out_hdw[i]  = hdw;
    out_nemb[i] = (hdw / ws_debias[0]) / ws_stable[kk];
}

// ---------------- launch ------------------------------------------------------
extern "C" void kernel_launch(void* const* d_in, const int* in_sizes, int n_in,
                              void* d_out, int out_size, void* d_ws, size_t ws_size,
                              hipStream_t stream)
{
    const float* x_in    = (const float*)d_in[0];   // [64,32,32,64]
    const float* emb     = (const float*)d_in[1];   // [64,512]
    const float* ema_csh = (const float*)d_in[2];   // [512]
    const float* ema_dwh = (const float*)d_in[3];   // [64,512]
    const int*   counter = (const int*)d_in[4];     // [1]

    float* ws  = (float*)d_ws;
    float* out = (float*)d_out;

    vq_prep<<<128, 256, 0, stream>>>(emb, ws);

    vq_main<<<NROWS / RPB, 256, 0, stream>>>(
        x_in, ws + WS_ET, ws + WS_ESQ,
        out + OUT_Q, out + OUT_IDX,
        ws + WS_DWT, ws + WS_COUNTS, ws + WS_LOSS);

    vq_final_a<<<1, K, 0, stream>>>(
        ws + WS_COUNTS, ws + WS_LOSS, ema_csh, counter,
        out + OUT_LOSS, out + OUT_PERP, out + OUT_HCS,
        ws + WS_STABLE, ws + WS_DEBIAS);

    vq_final_b<<<128, 256, 0, stream>>>(
        ws + WS_DWT, ema_dwh, ws + WS_STABLE, ws + WS_DEBIAS,
        out + OUT_NEMB, out + OUT_HDW);
}

// Round 5
// 174.605 us; speedup vs baseline: 3.0763x; 3.0763x over previous
//
#include <hip/hip_runtime.h>
#include <hip/hip_bf16.h>
#include <math.h>

// Problem constants (from reference)
#define D 64
#define K 512
#define NROWS 65536
#define DECAY 0.99f
#define ONE_MINUS_DECAY (1.0f - 0.99f)
#define COMMIT 0.25f

// ws layout (float offsets)
#define WS_DWT    0              // [K][D] = 32768  dw accumulator (transposed)
#define WS_COUNTS 32768          // [K]   = 512     cluster counts
#define WS_LOSS   33280          // [1]             loss sum (pad to 33344)
#define WS_ESQ    33344          // [K]   = 512     ||e_k||^2
#define WS_ET     33856          // [K][D]= 32768   embeddings transposed
#define WS_STABLE 66624          // [K]   = 512     stable_cs
#define WS_DEBIAS 67136          // [1]             debias factor
#define WS_ZERO_FLOATS 33344     // zero region: dw_t + counts + loss (+pad)

// out layout (float offsets)
#define OUT_Q     0              // quantized_st [N][D]
#define OUT_LOSS  4194304
#define OUT_PERP  4194305
#define OUT_IDX   4194306        // [N] indices as float
#define OUT_NEMB  4259842        // new_embeddings [D][K]
#define OUT_HCS   4292610        // hid_cs [K]
#define OUT_HDW   4293122        // hid_dw [D][K]

// main-kernel tiling (round-1 structure: PLAIN layouts, zero bank conflicts)
#define BM 64                    // rows per block
#define BK 128                   // codebook columns per chunk
#define NCHUNK (K / BK)

// ---------------- prep: zero accumulators + transpose emb + col norms -------
__global__ void vq_prep(const float* __restrict__ emb,  // [D][K]
                        float* __restrict__ ws)
{
    int i = blockIdx.x * 256 + threadIdx.x;   // 0..32767 (128 blocks)
    if (i < WS_ZERO_FLOATS / 4) {             // zero dw_t + counts + loss
        ((float4*)ws)[i] = make_float4(0.f, 0.f, 0.f, 0.f);
    }
    {                                         // e_t[k][d] = emb[d][k] (coalesced write)
        int k = i >> 6, d = i & 63;
        ws[WS_ET + i] = emb[d * K + k];
    }
    if (i < K) {                              // ||e_k||^2 (coalesced over k)
        float s = 0.f;
        for (int d = 0; d < D; ++d) { float v = emb[d * K + i]; s += v * v; }
        ws[WS_ESQ + i] = s;
    }
}

// ---------------- main: distances + argmin + gather + scatter ----------------
__global__ __launch_bounds__(256, 3)
void vq_main(const float* __restrict__ x,     // [N][D]
             const float* __restrict__ emb,   // [D][K]
             const float* __restrict__ e_sq,  // [K]
             const float* __restrict__ e_t,   // [K][D]
             float* __restrict__ out_q,       // [N][D]
             float* __restrict__ out_idx,     // [N] (float)
             float* __restrict__ dw_t,        // [K][D] atomic accum
             float* __restrict__ counts,      // [K]  atomic accum
             float* __restrict__ loss_sum)    // [1]  atomic accum
{
    __shared__ float xs[BM * D];       // 16 KB, plain [row][d]
    __shared__ float es[D * BK];       // 32 KB, plain [d][col]
    __shared__ float esq_s[BK];
    __shared__ int   idx_s[BM];
    __shared__ float red_s[4];

    const int tid  = threadIdx.x;
    const int row0 = blockIdx.x * BM;

    // stage x tile (coalesced float4, plain layout)
    {
        const float4* src = (const float4*)(x + (size_t)row0 * D);
        float4* dst = (float4*)xs;
        for (int i = tid; i < BM * D / 4; i += 256) dst[i] = src[i];
    }

    const int tx = tid & 31;   // column group 0..31 (4 cols each)
    const int ty = tid >> 5;   // row group 0..7 (8 rows each)

    float best[8];
    int   bestk[8];
#pragma unroll
    for (int r = 0; r < 8; ++r) { best[r] = 3.0e38f; bestk[r] = 0; }

    for (int c = 0; c < NCHUNK; ++c) {
        __syncthreads();  // xs staged / previous chunk's es consumers done
        for (int i = tid * 4; i < D * BK; i += 1024) {
            int d = i >> 7, j = i & 127;
            *(float4*)&es[d * BK + j] = *(const float4*)&emb[d * K + c * BK + j];
        }
        if (tid < BK / 4)
            *(float4*)&esq_s[tid * 4] = *(const float4*)&e_sq[c * BK + tid * 4];
        __syncthreads();

        float acc[8][4];
#pragma unroll
        for (int r = 0; r < 8; ++r)
#pragma unroll
            for (int j = 0; j < 4; ++j) acc[r][j] = 0.f;

#pragma unroll 2
        for (int d0 = 0; d0 < D; d0 += 4) {
            // 4 e-vectors (b128, stride-1 lane sweep: conflict-free)
            float4 e4[4];
#pragma unroll
            for (int dd = 0; dd < 4; ++dd)
                e4[dd] = *(const float4*)&es[(d0 + dd) * BK + tx * 4];
            // 8 x-vectors (b128, 2 distinct addrs/wave: broadcast, ~free)
#pragma unroll
            for (int r = 0; r < 8; ++r) {
                float4 x4 = *(const float4*)&xs[(ty * 8 + r) * D + d0];
                acc[r][0] = fmaf(x4.x, e4[0].x, acc[r][0]);
                acc[r][1] = fmaf(x4.x, e4[0].y, acc[r][1]);
                acc[r][2] = fmaf(x4.x, e4[0].z, acc[r][2]);
                acc[r][3] = fmaf(x4.x, e4[0].w, acc[r][3]);
                acc[r][0] = fmaf(x4.y, e4[1].x, acc[r][0]);
                acc[r][1] = fmaf(x4.y, e4[1].y, acc[r][1]);
                acc[r][2] = fmaf(x4.y, e4[1].z, acc[r][2]);
                acc[r][3] = fmaf(x4.y, e4[1].w, acc[r][3]);
                acc[r][0] = fmaf(x4.z, e4[2].x, acc[r][0]);
                acc[r][1] = fmaf(x4.z, e4[2].y, acc[r][1]);
                acc[r][2] = fmaf(x4.z, e4[2].z, acc[r][2]);
                acc[r][3] = fmaf(x4.z, e4[2].w, acc[r][3]);
                acc[r][0] = fmaf(x4.w, e4[3].x, acc[r][0]);
                acc[r][1] = fmaf(x4.w, e4[3].y, acc[r][1]);
                acc[r][2] = fmaf(x4.w, e4[3].z, acc[r][2]);
                acc[r][3] = fmaf(x4.w, e4[3].w, acc[r][3]);
            }
        }
        // fold into running argmin (score = ||e||^2 - 2 x.e)
#pragma unroll
        for (int r = 0; r < 8; ++r) {
#pragma unroll
            for (int j = 0; j < 4; ++j) {
                float s = esq_s[tx * 4 + j] - 2.0f * acc[r][j];
                int   kk = c * BK + tx * 4 + j;
                if (s < best[r]) { best[r] = s; bestk[r] = kk; }  // k ascends
            }
        }
    }

    // reduce argmin across the 32 lanes of each half-wave (same ty)
#pragma unroll
    for (int r = 0; r < 8; ++r) {
        float b = best[r]; int bk = bestk[r];
        for (int m = 16; m >= 1; m >>= 1) {
            float ob  = __shfl_xor(b, m, 64);
            int   obk = __shfl_xor(bk, m, 64);
            if (ob < b || (ob == b && obk < bk)) { b = ob; bk = obk; }
        }
        if (tx == 0) idx_s[ty * 8 + r] = bk;
    }
    __syncthreads();

    // quantized gather + loss partial
    float lsum = 0.f;
    for (int i = tid * 4; i < BM * D; i += 1024) {
        int r = i >> 6, d = i & 63;
        int kk = idx_s[r];
        float4 q  = *(const float4*)&e_t[kk * D + d];
        float4 xv = *(const float4*)&xs[r * D + d];
        float dx = q.x - xv.x, dy = q.y - xv.y, dz = q.z - xv.z, dwv = q.w - xv.w;
        lsum += dx * dx + dy * dy + dz * dz + dwv * dwv;
        *(float4*)&out_q[(size_t)(row0 + r) * D + d] = q;
    }
    for (int m = 32; m >= 1; m >>= 1) lsum += __shfl_xor(lsum, m, 64);
    if ((tid & 63) == 0) red_s[tid >> 6] = lsum;
    __syncthreads();
    if (tid == 0)
        atomicAdd(loss_sum, red_s[0] + red_s[1] + red_s[2] + red_s[3]);

    // indices + counts
    if (tid < BM) {
        int kk = idx_s[tid];
        out_idx[row0 + tid] = (float)kk;
        atomicAdd(&counts[kk], 1.0f);
    }

    // dw scatter: whole wave on one row, consecutive d -> coalesced atomics
    for (int i = tid; i < BM * D; i += 256) {
        int r = i >> 6, d = i & 63;
        atomicAdd(&dw_t[idx_s[r] * D + d], xs[r * D + d]);
    }
}

// ---------------- finalize A: scalars (1 block, shuffle reductions) ----------
__global__ void vq_final_a(const float* __restrict__ counts,
                           const float* __restrict__ loss_sum,
                           const float* __restrict__ ema_csh,  // [K]
                           const int*   __restrict__ counter,
                           float* __restrict__ out_loss,
                           float* __restrict__ out_perp,
                           float* __restrict__ out_hcs,        // [K]
                           float* __restrict__ ws_stable,      // [K]
                           float* __restrict__ ws_debias)      // [1]
{
    __shared__ float pn[8], pe[8];

    const int k    = threadIdx.x;  // 512 threads = 8 waves
    const int lane = k & 63;
    const int wv   = k >> 6;

    const float c   = counts[k];
    const float hid = ema_csh[k] * DECAY + c * ONE_MINUS_DECAY;
    out_hcs[k] = hid;

    const int   cnt    = counter[0] + 1;
    const float debias = 1.0f - powf(DECAY, (float)cnt);
    const float upd    = hid / debias;

    const float p = c * (1.0f / (float)NROWS);
    float a = upd;
    float b = p * logf(p + 1e-10f);
    for (int m = 32; m >= 1; m >>= 1) {
        a += __shfl_xor(a, m, 64);
        b += __shfl_xor(b, m, 64);
    }
    if (lane == 0) { pn[wv] = a; pe[wv] = b; }
    __syncthreads();

    float n = 0.f, ent = 0.f;
#pragma unroll
    for (int i = 0; i < 8; ++i) { n += pn[i]; ent += pe[i]; }

    ws_stable[k] = (upd + 1e-5f) / (n + (float)K * 1e-5f) * n;
    if (k == 0) {
        ws_debias[0] = debias;
        out_loss[0]  = COMMIT * loss_sum[0] / (float)((size_t)NROWS * D);
        out_perp[0]  = expf(-ent);
    }
}

// ---------------- finalize B: hdw + new embeddings (parallel) ----------------
__global__ void vq_final_b(const float* __restrict__ dw_t,      // [K][D]
                           const float* __restrict__ ema_dwh,   // [D][K]
                           const float* __restrict__ ws_stable, // [K]
                           const float* __restrict__ ws_debias,
                           float* __restrict__ out_nemb,        // [D][K]
                           float* __restrict__ out_hdw)         // [D][K]
{
    int i = blockIdx.x * 256 + threadIdx.x;  // 0..32767 (128 blocks)
    int d = i >> 9, kk = i & (K - 1);
    float hdw = ema_dwh[i] * DECAY + dw_t[kk * D + d] * ONE_MINUS_DECAY;
    out_hdw[i]  = hdw;
    out_nemb[i] = (hdw / ws_debias[0]) / ws_stable[kk];
}

// ---------------- launch ------------------------------------------------------
extern "C" void kernel_launch(void* const* d_in, const int* in_sizes, int n_in,
                              void* d_out, int out_size, void* d_ws, size_t ws_size,
                              hipStream_t stream)
{
    const float* x_in    = (const float*)d_in[0];   // [64,32,32,64]
    const float* emb     = (const float*)d_in[1];   // [64,512]
    const float* ema_csh = (const float*)d_in[2];   // [512]
    const float* ema_dwh = (const float*)d_in[3];   // [64,512]
    const int*   counter = (const int*)d_in[4];     // [1]

    float* ws  = (float*)d_ws;
    float* out = (float*)d_out;

    vq_prep<<<128, 256, 0, stream>>>(emb, ws);

    vq_main<<<NROWS / BM, 256, 0, stream>>>(
        x_in, emb, ws + WS_ESQ, ws + WS_ET,
        out + OUT_Q, out + OUT_IDX,
        ws + WS_DWT, ws + WS_COUNTS, ws + WS_LOSS);

    vq_final_a<<<1, K, 0, stream>>>(
        ws + WS_COUNTS, ws + WS_LOSS, ema_csh, counter,
        out + OUT_LOSS, out + OUT_PERP, out + OUT_HCS,
        ws + WS_STABLE, ws + WS_DEBIAS);

    vq_final_b<<<128, 256, 0, stream>>>(
        ws + WS_DWT, ema_dwh, ws + WS_STABLE, ws + WS_DEBIAS,
        out + OUT_NEMB, out + OUT_HDW);
}

// Round 6
// 172.260 us; speedup vs baseline: 3.1181x; 1.0136x over previous
//
#include <hip/hip_runtime.h>
#include <hip/hip_bf16.h>
#include <math.h>

// Problem constants (from reference)
#define D 64
#define K 512
#define NROWS 65536
#define DECAY 0.99f
#define ONE_MINUS_DECAY (1.0f - 0.99f)
#define COMMIT 0.25f

// ws layout (float offsets)
#define WS_DWT    0              // [K][D] = 32768  dw accumulator (transposed)
#define WS_COUNTS 32768          // [K]   = 512     cluster counts
#define WS_LOSS   33280          // [1]             loss sum (pad to 33344)
#define WS_ESQ    33344          // [K]   = 512     ||e_k||^2
#define WS_ET     33856          // [K][D]= 32768   embeddings transposed
#define WS_STABLE 66624          // [K]   = 512     stable_cs
#define WS_DEBIAS 67136          // [1]             debias factor
#define WS_ZERO_FLOATS 33344     // zero region: dw_t + counts + loss (+pad)

// out layout (float offsets)
#define OUT_Q     0              // quantized_st [N][D]
#define OUT_LOSS  4194304
#define OUT_PERP  4194305
#define OUT_IDX   4194306        // [N] indices as float
#define OUT_NEMB  4259842        // new_embeddings [D][K]
#define OUT_HCS   4292610        // hid_cs [K]
#define OUT_HDW   4293122        // hid_dw [D][K]

// main-kernel tiling: 8x8 register tile per thread, 256 threads
#define BM 128                   // rows per block
#define BN 128                   // codebook columns per chunk
#define NCHUNK (K / BN)
#define XS_STRIDE 68             // 68 mod 32 = 4 -> consecutive sigma on distinct quads
#define ES_CG_STRIDE 516         // 516 mod 32 = 4 -> 16 tx at 2-way max (free)

// xs row permutation: sigma(row) = ((row&7)<<4)|(row>>3); row = ty*8+r ->
// sigma = r*16+ty, so the 4 concurrent ty's of one x-read are CONSECUTIVE
// sigma -> addr delta 68 = 4 mod 32 -> 4 distinct bank quads, conflict-free.
// 68*4 B = 272 = 17*16 -> float4 alignment preserved. Max idx 127*68+63=8699.
__device__ __forceinline__ int xs_base(int row) {
    return (((row & 7) << 4) | (row >> 3)) * XS_STRIDE;
}

// ---------------- prep: zero accumulators + transpose emb + col norms -------
__global__ void vq_prep(const float* __restrict__ emb,  // [D][K]
                        float* __restrict__ ws)
{
    int i = blockIdx.x * 256 + threadIdx.x;   // 0..32767 (128 blocks)
    if (i < WS_ZERO_FLOATS / 4) {             // zero dw_t + counts + loss
        ((float4*)ws)[i] = make_float4(0.f, 0.f, 0.f, 0.f);
    }
    {                                         // e_t[k][d] = emb[d][k]
        int k = i >> 6, d = i & 63;
        ws[WS_ET + i] = emb[d * K + k];
    }
    if (i < K) {                              // ||e_k||^2
        float s = 0.f;
        for (int d = 0; d < D; ++d) { float v = emb[d * K + i]; s += v * v; }
        ws[WS_ESQ + i] = s;
    }
}

// ---------------- main: distances + argmin + gather + scatter ----------------
__global__ __launch_bounds__(256, 2)
void vq_main(const float* __restrict__ x,     // [N][D]
             const float* __restrict__ emb,   // [D][K]
             const float* __restrict__ e_sq,  // [K]
             const float* __restrict__ e_t,   // [K][D]
             float* __restrict__ out_q,       // [N][D]
             float* __restrict__ out_idx,     // [N] (float)
             float* __restrict__ dw_t,        // [K][D] atomic accum
             float* __restrict__ counts,      // [K]  atomic accum
             float* __restrict__ loss_sum)    // [1]  atomic accum
{
    __shared__ float xs[BM * XS_STRIDE + 4];  // 8708 fl (34.8 KB)
    __shared__ float es[16 * ES_CG_STRIDE];   // 8256 fl (33.0 KB)
    __shared__ float esq_s[BN];
    __shared__ int   idx_s[BM];
    __shared__ float red_s[4];

    const int tid  = threadIdx.x;
    const int row0 = blockIdx.x * BM;
    const int tx   = tid & 15;   // col group: cols tx*8 .. tx*8+7
    const int ty   = tid >> 4;   // row group: rows ty*8 .. ty*8+7 (via sigma)

    // ---- prefetch e chunk 0 into registers (8 float4/thread, coalesced) ----
    float4 epf[8];
#pragma unroll
    for (int t = 0; t < 8; ++t) {
        int f4 = tid + t * 256;            // 0..2047 float4s of the 64x128 chunk
        int d = f4 >> 5, j4 = f4 & 31;
        epf[t] = *(const float4*)&emb[d * K + j4 * 4];
    }

    // ---- stage x tile (coalesced read, sigma-swizzled write) ----
#pragma unroll
    for (int t = 0; t < 8; ++t) {
        int m = tid + t * 256;             // 0..2047 float4s of the 128x64 tile
        int row = m >> 4, seg = m & 15;
        float4 v = *(const float4*)(x + (size_t)(row0 + row) * D + seg * 4);
        *(float4*)&xs[xs_base(row) + seg * 4] = v;
    }

    // per-thread xs bases for its 8 rows: sigma(ty*8+r) = r*16+ty
    int xb[8];
#pragma unroll
    for (int r = 0; r < 8; ++r) xb[r] = ((r << 4) | ty) * XS_STRIDE;

    float best[8];
    int   bestk[8];
#pragma unroll
    for (int r = 0; r < 8; ++r) { best[r] = 3.0e38f; bestk[r] = 0; }

    for (int c = 0; c < NCHUNK; ++c) {
        __syncthreads();  // prev chunk's es consumers done / xs staged
        // dump prefetched e regs -> LDS (vmcnt wait covers only epf loads)
#pragma unroll
        for (int t = 0; t < 8; ++t) {
            int f4 = tid + t * 256;
            int d = f4 >> 5, j4 = f4 & 31;
            *(float4*)&es[(j4 >> 1) * ES_CG_STRIDE + d * 8 + (j4 & 1) * 4] = epf[t];
        }
        if (tid < 32)
            *(float4*)&esq_s[tid * 4] = *(const float4*)&e_sq[c * BN + tid * 4];
        __syncthreads();
        // issue next chunk's prefetch NOW; its vmcnt is waited at the NEXT
        // dump, i.e. hidden behind this chunk's ~2048 FMAs
        if (c < NCHUNK - 1) {
#pragma unroll
            for (int t = 0; t < 8; ++t) {
                int f4 = tid + t * 256;
                int d = f4 >> 5, j4 = f4 & 31;
                epf[t] = *(const float4*)&emb[d * K + (c + 1) * BN + j4 * 4];
            }
        }

        float acc[8][8];
#pragma unroll
        for (int r = 0; r < 8; ++r)
#pragma unroll
            for (int j = 0; j < 8; ++j) acc[r][j] = 0.f;

#pragma unroll 2
        for (int d0 = 0; d0 < D; d0 += 4) {
            float4 ea[4], eb[4];
#pragma unroll
            for (int dd = 0; dd < 4; ++dd) {
                const float* rp = &es[tx * ES_CG_STRIDE + (d0 + dd) * 8];
                ea[dd] = *(const float4*)rp;
                eb[dd] = *(const float4*)(rp + 4);
            }
#pragma unroll
            for (int r = 0; r < 8; ++r) {
                float4 x4 = *(const float4*)&xs[xb[r] + d0];
                float xv[4] = {x4.x, x4.y, x4.z, x4.w};
#pragma unroll
                for (int dd = 0; dd < 4; ++dd) {
                    acc[r][0] = fmaf(xv[dd], ea[dd].x, acc[r][0]);
                    acc[r][1] = fmaf(xv[dd], ea[dd].y, acc[r][1]);
                    acc[r][2] = fmaf(xv[dd], ea[dd].z, acc[r][2]);
                    acc[r][3] = fmaf(xv[dd], ea[dd].w, acc[r][3]);
                    acc[r][4] = fmaf(xv[dd], eb[dd].x, acc[r][4]);
                    acc[r][5] = fmaf(xv[dd], eb[dd].y, acc[r][5]);
                    acc[r][6] = fmaf(xv[dd], eb[dd].z, acc[r][6]);
                    acc[r][7] = fmaf(xv[dd], eb[dd].w, acc[r][7]);
                }
            }
        }

        // fold into running per-row argmin (score = ||e||^2 - 2 x.e)
#pragma unroll
        for (int r = 0; r < 8; ++r) {
#pragma unroll
            for (int j = 0; j < 8; ++j) {
                float s = esq_s[tx * 8 + j] - 2.0f * acc[r][j];
                int   kk = c * BN + tx * 8 + j;
                if (s < best[r]) { best[r] = s; bestk[r] = kk; }  // k ascends
            }
        }
    }

    // reduce argmin across the 16 lanes sharing ty (xor within lane&15)
#pragma unroll
    for (int r = 0; r < 8; ++r) {
        float b = best[r]; int bk = bestk[r];
        for (int m = 8; m >= 1; m >>= 1) {
            float ob  = __shfl_xor(b, m, 64);
            int   obk = __shfl_xor(bk, m, 64);
            if (ob < b || (ob == b && obk < bk)) { b = ob; bk = obk; }
        }
        if (tx == 0) idx_s[ty * 8 + r] = bk;
    }
    __syncthreads();

    // quantized gather + loss partial (16 lanes cover one row's 64 floats)
    float lsum = 0.f;
    for (int i = tid * 4; i < BM * D; i += 1024) {
        int r = i >> 6, d = i & 63;
        int kk = idx_s[r];
        float4 q  = *(const float4*)&e_t[kk * D + d];
        float4 xv = *(const float4*)&xs[xs_base(r) + d];
        float d0 = q.x - xv.x, d1 = q.y - xv.y, d2 = q.z - xv.z, d3 = q.w - xv.w;
        lsum += d0 * d0 + d1 * d1 + d2 * d2 + d3 * d3;
        *(float4*)&out_q[(size_t)(row0 + r) * D + d] = q;
    }
    for (int m = 32; m >= 1; m >>= 1) lsum += __shfl_xor(lsum, m, 64);
    if ((tid & 63) == 0) red_s[tid >> 6] = lsum;
    __syncthreads();
    if (tid == 0)
        atomicAdd(loss_sum, red_s[0] + red_s[1] + red_s[2] + red_s[3]);

    // indices + counts
    if (tid < BM) {
        int kk = idx_s[tid];
        out_idx[row0 + tid] = (float)kk;
        atomicAdd(&counts[kk], 1.0f);
    }

    // dw scatter: whole wave sweeps one row's 64 d -> coalesced atomics
    for (int i = tid; i < BM * D; i += 256) {
        int r = i >> 6, d = i & 63;
        atomicAdd(&dw_t[idx_s[r] * D + d], xs[xs_base(r) + d]);
    }
}

// ---------------- finalize A: scalars (1 block, shuffle reductions) ----------
__global__ void vq_final_a(const float* __restrict__ counts,
                           const float* __restrict__ loss_sum,
                           const float* __restrict__ ema_csh,  // [K]
                           const int*   __restrict__ counter,
                           float* __restrict__ out_loss,
                           float* __restrict__ out_perp,
                           float* __restrict__ out_hcs,        // [K]
                           float* __restrict__ ws_stable,      // [K]
                           float* __restrict__ ws_debias)      // [1]
{
    __shared__ float pn[8], pe[8];

    const int k    = threadIdx.x;  // 512 threads = 8 waves
    const int lane = k & 63;
    const int wv   = k >> 6;

    const float c   = counts[k];
    const float hid = ema_csh[k] * DECAY + c * ONE_MINUS_DECAY;
    out_hcs[k] = hid;

    const int   cnt    = counter[0] + 1;
    const float debias = 1.0f - powf(DECAY, (float)cnt);
    const float upd    = hid / debias;

    const float p = c * (1.0f / (float)NROWS);
    float a = upd;
    float b = p * logf(p + 1e-10f);
    for (int m = 32; m >= 1; m >>= 1) {
        a += __shfl_xor(a, m, 64);
        b += __shfl_xor(b, m, 64);
    }
    if (lane == 0) { pn[wv] = a; pe[wv] = b; }
    __syncthreads();

    float n = 0.f, ent = 0.f;
#pragma unroll
    for (int i = 0; i < 8; ++i) { n += pn[i]; ent += pe[i]; }

    ws_stable[k] = (upd + 1e-5f) / (n + (float)K * 1e-5f) * n;
    if (k == 0) {
        ws_debias[0] = debias;
        out_loss[0]  = COMMIT * loss_sum[0] / (float)((size_t)NROWS * D);
        out_perp[0]  = expf(-ent);
    }
}

// ---------------- finalize B: hdw + new embeddings (parallel) ----------------
__global__ void vq_final_b(const float* __restrict__ dw_t,      // [K][D]
                           const float* __restrict__ ema_dwh,   // [D][K]
                           const float* __restrict__ ws_stable, // [K]
                           const float* __restrict__ ws_debias,
                           float* __restrict__ out_nemb,        // [D][K]
                           float* __restrict__ out_hdw)         // [D][K]
{
    int i = blockIdx.x * 256 + threadIdx.x;  // 0..32767 (128 blocks)
    int d = i >> 9, kk = i & (K - 1);
    float hdw = ema_dwh[i] * DECAY + dw_t[kk * D + d] * ONE_MINUS_DECAY;
    out_hdw[i]  = hdw;
    out_nemb[i] = (hdw / ws_debias[0]) / ws_stable[kk];
}

// ---------------- launch ------------------------------------------------------
extern "C" void kernel_launch(void* const* d_in, const int* in_sizes, int n_in,
                              void* d_out, int out_size, void* d_ws, size_t ws_size,
                              hipStream_t stream)
{
    const float* x_in    = (const float*)d_in[0];   // [64,32,32,64]
    const float* emb     = (const float*)d_in[1];   // [64,512]
    const float* ema_csh = (const float*)d_in[2];   // [512]
    const float* ema_dwh = (const float*)d_in[3];   // [64,512]
    const int*   counter = (const int*)d_in[4];     // [1]

    float* ws  = (float*)d_ws;
    float* out = (float*)d_out;

    vq_prep<<<128, 256, 0, stream>>>(emb, ws);

    vq_main<<<NROWS / BM, 256, 0, stream>>>(
        x_in, emb, ws + WS_ESQ, ws + WS_ET,
        out + OUT_Q, out + OUT_IDX,
        ws + WS_DWT, ws + WS_COUNTS, ws + WS_LOSS);

    vq_final_a<<<1, K, 0, stream>>>(
        ws + WS_COUNTS, ws + WS_LOSS, ema_csh, counter,
        out + OUT_LOSS, out + OUT_PERP, out + OUT_HCS,
        ws + WS_STABLE, ws + WS_DEBIAS);

    vq_final_b<<<128, 256, 0, stream>>>(
        ws + WS_DWT, ema_dwh, ws + WS_STABLE, ws + WS_DEBIAS,
        out + OUT_NEMB, out + OUT_HDW);
}